// Round 1
// baseline (667.743 us; speedup 1.0000x reference)
//
#include <hip/hip_runtime.h>
#include <math.h>

#define CF 768
#define BB 32
#define MM 32
#define HW 784
#define NH 1024
#define MCF 24576  // M*CF
#define BETA 0.05f

// ---------------- Kernel A: V[b][m*CF+c] = (1/784) sum_hw F[b][c][hw]*A[b][m][hw]
// grid: 32*16 blocks (b, c-tile of 48), 256 threads
#define CTILE 48
#define CHUNK 392

__global__ __launch_bounds__(256) void kA(const float* __restrict__ F,
                                          const float* __restrict__ A,
                                          float* __restrict__ V) {
    __shared__ float As[32][CHUNK + 1];
    __shared__ float Fs[4][CHUNK + 1];
    int b = blockIdx.x >> 4;
    int cbase = (blockIdx.x & 15) * CTILE;
    int t = threadIdx.x;
    int s = t & 7;
    int m = t >> 3;
    float acc[12][4];
    #pragma unroll
    for (int g = 0; g < 12; ++g)
        #pragma unroll
        for (int c = 0; c < 4; ++c) acc[g][c] = 0.f;
    for (int ch = 0; ch < 2; ++ch) {
        int hwb = ch * CHUNK;
        __syncthreads();
        const float* Ab = A + (size_t)b * MM * HW;
        for (int idx = t; idx < 32 * CHUNK; idx += 256) {
            int mm = idx / CHUNK;
            int hw = idx - mm * CHUNK;
            As[mm][hw] = Ab[mm * HW + hwb + hw];
        }
        for (int cg = 0; cg < 12; ++cg) {
            __syncthreads();
            const float* Fb = F + ((size_t)b * CF + cbase + cg * 4) * HW + hwb;
            for (int idx = t; idx < 4 * CHUNK; idx += 256) {
                int cc = idx / CHUNK;
                int hw = idx - cc * CHUNK;
                Fs[cc][hw] = Fb[cc * HW + hw];
            }
            __syncthreads();
            for (int hw = s; hw < CHUNK; hw += 8) {
                float a = As[m][hw];
                #pragma unroll
                for (int cc = 0; cc < 4; ++cc)
                    acc[cg][cc] = fmaf(a, Fs[cc][hw], acc[cg][cc]);
            }
        }
    }
    #pragma unroll
    for (int cg = 0; cg < 12; ++cg) {
        #pragma unroll
        for (int cc = 0; cc < 4; ++cc) {
            float v = acc[cg][cc];
            v += __shfl_down(v, 4, 8);
            v += __shfl_down(v, 2, 8);
            v += __shfl_down(v, 1, 8);
            if (s == 0) V[(size_t)b * MCF + m * CF + cbase + cg * 4 + cc] = v * (1.f / 784.f);
        }
    }
}

// ---------------- Kernel B1: column sums -> C_new, per-block partial sum of diff^2
__global__ __launch_bounds__(256) void kB1(const float* __restrict__ V,
                                           const float* __restrict__ C,
                                           float* __restrict__ Cnew_out,
                                           float* __restrict__ partial) {
    int j = blockIdx.x * 256 + threadIdx.x;
    float c = C[j];
    float s = 0.f;
    for (int b = 0; b < 32; ++b) s += V[(size_t)b * MCF + j];
    float cn = c + BETA * (s * (1.f / 32.f) - c);
    Cnew_out[j] = cn;
    float ds = 0.f;
    for (int b = 0; b < 32; ++b) {
        float d = V[(size_t)b * MCF + j] - cn;
        ds = fmaf(d, d, ds);
    }
    __shared__ float red[256];
    red[threadIdx.x] = ds;
    __syncthreads();
    for (int off = 128; off > 0; off >>= 1) {
        if (threadIdx.x < off) red[threadIdx.x] += red[threadIdx.x + off];
        __syncthreads();
    }
    if (threadIdx.x == 0) partial[blockIdx.x] = red[0];
}

__global__ void kB2(const float* __restrict__ partial, float* __restrict__ out) {
    if (threadIdx.x == 0) {
        float s = 0.f;
        for (int i = 0; i < 96; ++i) s += partial[i];
        out[0] = s / (32.f * 24576.f);
    }
}

// ---------------- Kernel C: Xpre[t][g][b][j] = X_t @ Wxg^T + bxg + bhg
// rows r=(t,b) 1024, cols n=(g,j) 4096; 64x64 tiles
__global__ __launch_bounds__(256) void kC(const float* __restrict__ V,
    const float* __restrict__ Wxi, const float* __restrict__ Wxf,
    const float* __restrict__ Wxo, const float* __restrict__ Wxc,
    const float* __restrict__ bxi, const float* __restrict__ bxf,
    const float* __restrict__ bxo, const float* __restrict__ bxc,
    const float* __restrict__ bhi, const float* __restrict__ bhf,
    const float* __restrict__ bho, const float* __restrict__ bhc,
    float* __restrict__ Xpre) {
    __shared__ float As[64][17];
    __shared__ float Bs[64][17];
    int rbase = blockIdx.x * 64;
    int nbase = blockIdx.y * 64;
    int g = nbase >> 10;
    int jbase = nbase & 1023;
    const float* Wg  = (g == 0) ? Wxi : (g == 1) ? Wxf : (g == 2) ? Wxo : Wxc;
    const float* bxg = (g == 0) ? bxi : (g == 1) ? bxf : (g == 2) ? bxo : bxc;
    const float* bhg = (g == 0) ? bhi : (g == 1) ? bhf : (g == 2) ? bho : bhc;
    int t = threadIdx.x;
    int tx = t & 15, ty = t >> 4;
    float acc[4][4] = {};
    for (int k0 = 0; k0 < CF; k0 += 16) {
        __syncthreads();
        #pragma unroll
        for (int u = 0; u < 4; ++u) {
            int idx = t + u * 256;
            int row = idx >> 4, kl = idx & 15;
            int r = rbase + row;
            As[row][kl] = V[(size_t)(r & 31) * MCF + (r >> 5) * CF + k0 + kl];
            Bs[row][kl] = Wg[(size_t)(jbase + row) * CF + k0 + kl];
        }
        __syncthreads();
        #pragma unroll
        for (int kk = 0; kk < 16; ++kk) {
            float a[4], bv[4];
            #pragma unroll
            for (int i = 0; i < 4; ++i) a[i] = As[ty * 4 + i][kk];
            #pragma unroll
            for (int jj = 0; jj < 4; ++jj) bv[jj] = Bs[tx * 4 + jj][kk];
            #pragma unroll
            for (int i = 0; i < 4; ++i)
                #pragma unroll
                for (int jj = 0; jj < 4; ++jj)
                    acc[i][jj] = fmaf(a[i], bv[jj], acc[i][jj]);
        }
    }
    #pragma unroll
    for (int jj = 0; jj < 4; ++jj) {
        int c = tx * 4 + jj;
        float bias = bxg[jbase + c] + bhg[jbase + c];
        #pragma unroll
        for (int i = 0; i < 4; ++i) {
            int r = rbase + ty * 4 + i;
            int tt = r >> 5, bb = r & 31;
            Xpre[(((size_t)tt * 4 + g) * 32 + bb) * 1024 + jbase + c] = acc[i][jj] + bias;
        }
    }
}

// ---------------- Kernel P: partial H @ Whg^T for one step, k split 8 ways
// 256 blocks: jg = blk>>3 (32 units each), ks = blk&7 (128 k's each)
__global__ __launch_bounds__(256) void kP(const float* __restrict__ H,
    const float* __restrict__ Whi, const float* __restrict__ Whf,
    const float* __restrict__ Who, const float* __restrict__ Whc,
    float* __restrict__ Pbuf) {
    __shared__ float Hs[32][132];
    int blk = blockIdx.x;
    int jg = blk >> 3, ks = blk & 7;
    int jbase = jg * 32, kbase = ks * 128;
    int t = threadIdx.x;
    for (int idx = t; idx < 32 * 128; idx += 256) {
        int b = idx >> 7, k = idx & 127;
        Hs[b][k] = H[b * 1024 + kbase + k];
    }
    __syncthreads();
    int bq = t & 7, gjq = t >> 3;  // gjq in 0..31
    int j = jbase + gjq;
    const float* W0 = Whi + (size_t)j * 1024 + kbase;
    const float* W1 = Whf + (size_t)j * 1024 + kbase;
    const float* W2 = Who + (size_t)j * 1024 + kbase;
    const float* W3 = Whc + (size_t)j * 1024 + kbase;
    float acc[4][4] = {};  // [gate q][b-sub i]
    #pragma unroll 4
    for (int k4 = 0; k4 < 32; ++k4) {
        float4 h[4];
        #pragma unroll
        for (int i = 0; i < 4; ++i)
            h[i] = *(const float4*)&Hs[bq * 4 + i][k4 * 4];
        float4 w0 = *(const float4*)&W0[k4 * 4];
        float4 w1 = *(const float4*)&W1[k4 * 4];
        float4 w2 = *(const float4*)&W2[k4 * 4];
        float4 w3 = *(const float4*)&W3[k4 * 4];
        #pragma unroll
        for (int i = 0; i < 4; ++i) {
            acc[0][i] = fmaf(h[i].x, w0.x, acc[0][i]); acc[0][i] = fmaf(h[i].y, w0.y, acc[0][i]);
            acc[0][i] = fmaf(h[i].z, w0.z, acc[0][i]); acc[0][i] = fmaf(h[i].w, w0.w, acc[0][i]);
            acc[1][i] = fmaf(h[i].x, w1.x, acc[1][i]); acc[1][i] = fmaf(h[i].y, w1.y, acc[1][i]);
            acc[1][i] = fmaf(h[i].z, w1.z, acc[1][i]); acc[1][i] = fmaf(h[i].w, w1.w, acc[1][i]);
            acc[2][i] = fmaf(h[i].x, w2.x, acc[2][i]); acc[2][i] = fmaf(h[i].y, w2.y, acc[2][i]);
            acc[2][i] = fmaf(h[i].z, w2.z, acc[2][i]); acc[2][i] = fmaf(h[i].w, w2.w, acc[2][i]);
            acc[3][i] = fmaf(h[i].x, w3.x, acc[3][i]); acc[3][i] = fmaf(h[i].y, w3.y, acc[3][i]);
            acc[3][i] = fmaf(h[i].z, w3.z, acc[3][i]); acc[3][i] = fmaf(h[i].w, w3.w, acc[3][i]);
        }
    }
    #pragma unroll
    for (int q = 0; q < 4; ++q)
        #pragma unroll
        for (int i = 0; i < 4; ++i)
            Pbuf[(((size_t)ks * 4 + q) * 32 + (bq * 4 + i)) * 1024 + j] = acc[q][i];
}

// ---------------- Kernel Cmb: sum partials + Xpre, gates, update C/H
__global__ __launch_bounds__(256) void kCmb(const float* __restrict__ Pbuf,
    const float* __restrict__ Xpre_t, float* __restrict__ Cst,
    float* __restrict__ Hout) {
    int u = blockIdx.x * 256 + threadIdx.x;  // 0..32767
    int b = u >> 10, j = u & 1023;
    float pre[4];
    #pragma unroll
    for (int g = 0; g < 4; ++g) {
        float s = Xpre_t[((size_t)g * 32 + b) * 1024 + j];
        #pragma unroll
        for (int ks = 0; ks < 8; ++ks)
            s += Pbuf[(((size_t)ks * 4 + g) * 32 + b) * 1024 + j];
        pre[g] = s;
    }
    float I  = 1.f / (1.f + __expf(-pre[0]));
    float Fg = 1.f / (1.f + __expf(-pre[1]));
    float O  = 1.f / (1.f + __expf(-pre[2]));
    float Ct = tanhf(pre[3]);
    float c = Fg * Cst[u] + I * Ct;
    Cst[u] = c;
    Hout[u] = O * tanhf(c);
}

extern "C" void kernel_launch(void* const* d_in, const int* in_sizes, int n_in,
                              void* d_out, int out_size, void* d_ws, size_t ws_size,
                              hipStream_t stream) {
    const float* F   = (const float*)d_in[0];
    const float* A   = (const float*)d_in[1];
    const float* C   = (const float*)d_in[2];
    const float* Wxi = (const float*)d_in[3];
    const float* bxi = (const float*)d_in[4];
    const float* Whi = (const float*)d_in[5];
    const float* bhi = (const float*)d_in[6];
    const float* Wxf = (const float*)d_in[7];
    const float* bxf = (const float*)d_in[8];
    const float* Whf = (const float*)d_in[9];
    const float* bhf = (const float*)d_in[10];
    const float* Wxo = (const float*)d_in[11];
    const float* bxo = (const float*)d_in[12];
    const float* Who = (const float*)d_in[13];
    const float* bho = (const float*)d_in[14];
    const float* Wxc = (const float*)d_in[15];
    const float* bxc = (const float*)d_in[16];
    const float* Whc = (const float*)d_in[17];
    const float* bhc = (const float*)d_in[18];

    float* out   = (float*)d_out;
    float* outH  = out;           // 32768 floats
    float* outRC = out + 32768;   // 1 float
    float* outC  = out + 32769;   // 24576 floats

    float* ws   = (float*)d_ws;
    float* V    = ws;             // 786432
    float* Xpre = ws + 786432;    // 4194304
    float* Hbuf = ws + 4980736;   // 32768
    float* Cst  = ws + 5013504;   // 32768
    float* Pbuf = ws + 5046272;   // 1048576
    float* part = ws + 6094848;   // 96

    // zero H0 and C0 (contiguous)
    hipMemsetAsync(Hbuf, 0, 2 * 32768 * sizeof(float), stream);

    kA<<<dim3(512), 256, 0, stream>>>(F, A, V);
    kB1<<<dim3(96), 256, 0, stream>>>(V, C, outC, part);
    kB2<<<1, 64, 0, stream>>>(part, outRC);
    kC<<<dim3(16, 64), 256, 0, stream>>>(V, Wxi, Wxf, Wxo, Wxc,
                                         bxi, bxf, bxo, bxc,
                                         bhi, bhf, bho, bhc, Xpre);
    for (int t = 0; t < 32; ++t) {
        kP<<<256, 256, 0, stream>>>(Hbuf, Whi, Whf, Who, Whc, Pbuf);
        float* Hout = (t == 31) ? outH : Hbuf;
        kCmb<<<128, 256, 0, stream>>>(Pbuf, Xpre + (size_t)t * 131072, Cst, Hout);
    }
}